// Round 5
// baseline (154.232 us; speedup 1.0000x reference)
//
#include <hip/hip_runtime.h>

#define BATCH 8
#define NPTS  4096
#define BLOCK 256
#define Q     8              // query points per thread
#define CHUNK 128            // target points staged in LDS per block
#define NPER  32768          // BATCH*NPTS points per cloud
#define NQ    2              // query splits  (NQ*BLOCK*Q == NPTS)
#define NT    32             // target splits (NT*CHUNK   == NPTS)
#define NBLOCKS (NQ * NT * 2 * BATCH)   // 1024 -> 4 blocks/CU, 4 waves/SIMD

// ws layout:
//   float4 pk[65536]    : packed [x,y,z,|p|^2]; pred then gt
//   uint   minbuf[65536]: min d2 bits; pred-queries first, gt-queries second
//   uint   counter      : retirement counter for last-block reduction

// K0: pack points into float4 (xyz + squared norm), init mins, reset counter.
__global__ __launch_bounds__(256) void pack_init_kernel(
    const float* __restrict__ pred, const float* __restrict__ gt,
    float4* __restrict__ pk, unsigned int* __restrict__ minbuf,
    unsigned int* __restrict__ counter)
{
    const int j = blockIdx.x * 256 + threadIdx.x;     // 0..65535
    const float* src = (j < NPER) ? pred : gt;
    const float* p = src + (size_t)(j & (NPER - 1)) * 3;
    const float x = p[0], y = p[1], z = p[2];
    pk[j] = make_float4(x, y, z, fmaf(x, x, fmaf(y, y, z * z)));
    minbuf[j] = 0x7F800000u;                          // +inf
    if (j == 0) *counter = 0u;
}

// K1: grid (NQ, NT, 16). Each thread owns Q=8 queries, loops CHUNK=128 targets
// staged in LDS as [gx,gy,gz,g2]; tracks min(g2 - 2 p.g) (3 fma + min3 per
// 2 targets), folds |p|^2, atomicMin. The LAST block to retire reduces
// minbuf -> scalar output (threadfence + retirement-counter pattern).
__global__ __launch_bounds__(BLOCK) void chamfer_min_kernel(
    const float4* __restrict__ pk, unsigned int* __restrict__ minbuf,
    unsigned int* __restrict__ counter, float* __restrict__ out)
{
    const int z    = blockIdx.z;
    const int b    = z & 7;
    const int pass = z >> 3;
    const float4* query  = pk + (pass ? NPER : 0) + b * NPTS;
    const float4* target = pk + (pass ? 0 : NPER) + b * NPTS;
    unsigned int* outmin = minbuf + (pass ? NPER : 0) + b * NPTS;

    __shared__ float4 s[CHUNK];
    __shared__ double sd[BLOCK];
    __shared__ unsigned int s_last;

    const int tid   = threadIdx.x;
    const int nbase = blockIdx.x * (BLOCK * Q);
    const int c0    = blockIdx.y * CHUNK;

    if (tid < CHUNK) s[tid] = target[c0 + tid];

    float nx2[Q], ny2[Q], nz2[Q], p2[Q], mn[Q];
#pragma unroll
    for (int i = 0; i < Q; ++i) {
        const float4 qf = query[nbase + i * BLOCK + tid];
        nx2[i] = -2.0f * qf.x;
        ny2[i] = -2.0f * qf.y;
        nz2[i] = -2.0f * qf.z;
        p2[i]  = qf.w;
        mn[i]  = 3.0e38f;
    }
    __syncthreads();

#pragma unroll 4
    for (int t = 0; t < CHUNK; t += 2) {
        const float4 g0 = s[t];
        const float4 g1 = s[t + 1];
#pragma unroll
        for (int i = 0; i < Q; ++i) {
            float da = fmaf(g0.x, nx2[i], g0.w);
            da = fmaf(g0.y, ny2[i], da);
            da = fmaf(g0.z, nz2[i], da);
            float db = fmaf(g1.x, nx2[i], g1.w);
            db = fmaf(g1.y, ny2[i], db);
            db = fmaf(g1.z, nz2[i], db);
            mn[i] = fminf(mn[i], fminf(da, db));      // -> v_min3_f32
        }
    }

#pragma unroll
    for (int i = 0; i < Q; ++i) {
        const float d2 = fmaxf(p2[i] + mn[i], 0.0f);  // min squared distance
        atomicMin(&outmin[nbase + i * BLOCK + tid], __float_as_uint(d2));
    }

    // ---- last-block-retires final reduction ----
    __threadfence();                                  // my atomics visible device-wide
    __syncthreads();                                  // whole block done + fenced
    if (tid == 0) {
        s_last = (atomicAdd(counter, 1u) == NBLOCKS - 1) ? 1u : 0u;
    }
    __syncthreads();
    if (s_last) {
        double acc = 0.0;
        for (int i = tid; i < 2 * NPER; i += BLOCK) {
            const unsigned int u = __hip_atomic_load(
                &minbuf[i], __ATOMIC_RELAXED, __HIP_MEMORY_SCOPE_AGENT);
            acc += (double)sqrtf(__uint_as_float(u));
        }
        sd[tid] = acc;
        __syncthreads();
        for (int off = BLOCK / 2; off > 0; off >>= 1) {
            if (tid < off) sd[tid] += sd[tid + off];
            __syncthreads();
        }
        if (tid == 0) out[0] = (float)(sd[0] / (double)NPER);
    }
}

extern "C" void kernel_launch(void* const* d_in, const int* in_sizes, int n_in,
                              void* d_out, int out_size, void* d_ws, size_t ws_size,
                              hipStream_t stream) {
    const float* pred = (const float*)d_in[0];
    const float* gt   = (const float*)d_in[1];

    float4* pk           = (float4*)d_ws;                   // 1 MB
    unsigned int* minbuf = (unsigned int*)(pk + 2 * NPER);  // 256 KB
    unsigned int* counter = minbuf + 2 * NPER;

    pack_init_kernel<<<2 * NPER / 256, 256, 0, stream>>>(pred, gt, pk, minbuf, counter);

    dim3 grid(NQ, NT, 2 * BATCH);
    chamfer_min_kernel<<<grid, BLOCK, 0, stream>>>(pk, minbuf, counter, (float*)d_out);
}

// Round 6
// 50.742 us; speedup vs baseline: 3.0395x; 3.0395x over previous
//
#include <hip/hip_runtime.h>

#define BATCH 8
#define NPTS  4096
#define BLOCK 256
#define Q     16             // query points per thread (BLOCK*Q == NPTS)
#define CHUNK 64             // target points staged in LDS per block
#define NT    (NPTS / CHUNK) // 64 target chunks
#define NPER  32768          // BATCH*NPTS points per cloud
#define NQTOT (2 * NPER)     // 65536 query slots (both passes)

// ws layout:
//   float4 pk[65536]        : packed [x,y,z,|p|^2]; pred then gt      (1 MB)
//   float  partial[NT][65536]: per-chunk min d2 for each query slot   (16 MB)
//   double bsum[64]         : per-block partial sums from reduce1

// K0: pack points into float4 (xyz + squared norm).
__global__ __launch_bounds__(256) void pack_kernel(
    const float* __restrict__ pred, const float* __restrict__ gt,
    float4* __restrict__ pk)
{
    const int j = blockIdx.x * 256 + threadIdx.x;     // 0..65535
    const float* src = (j < NPER) ? pred : gt;
    const float* p = src + (size_t)(j & (NPER - 1)) * 3;
    const float x = p[0], y = p[1], z = p[2];
    pk[j] = make_float4(x, y, z, fmaf(x, x, fmaf(y, y, z * z)));
}

// K1: grid (1, NT, 16). Each thread owns Q=16 queries, loops CHUNK=64 targets
// staged in LDS as [gx,gy,gz,g2]; tracks min(g2 - 2 p.g) (3 fma + min3 per
// 2 targets), folds |p|^2, and writes its chunk-min to a PRIVATE slot:
// partial[chunk][qslot]. No atomics, no init dependency, no fences.
__global__ __launch_bounds__(BLOCK) void chamfer_min_kernel(
    const float4* __restrict__ pk, float* __restrict__ partial)
{
    const int z    = blockIdx.z;                      // 0..15 = pass*8 + b
    const int b    = z & 7;
    const int pass = z >> 3;
    const float4* query  = pk + (pass ? NPER : 0) + b * NPTS;
    const float4* target = pk + (pass ? 0 : NPER) + b * NPTS;

    __shared__ float4 s[CHUNK];

    const int tid = threadIdx.x;
    const int c0  = blockIdx.y * CHUNK;

    if (tid < CHUNK) s[tid] = target[c0 + tid];

    float nx2[Q], ny2[Q], nz2[Q], p2[Q], mn[Q];
#pragma unroll
    for (int i = 0; i < Q; ++i) {
        const float4 qf = query[i * BLOCK + tid];
        nx2[i] = -2.0f * qf.x;
        ny2[i] = -2.0f * qf.y;
        nz2[i] = -2.0f * qf.z;
        p2[i]  = qf.w;
        mn[i]  = 3.0e38f;
    }
    __syncthreads();

#pragma unroll 2
    for (int t = 0; t < CHUNK; t += 2) {
        const float4 g0 = s[t];
        const float4 g1 = s[t + 1];
#pragma unroll
        for (int i = 0; i < Q; ++i) {
            float da = fmaf(g0.x, nx2[i], g0.w);
            da = fmaf(g0.y, ny2[i], da);
            da = fmaf(g0.z, nz2[i], da);
            float db = fmaf(g1.x, nx2[i], g1.w);
            db = fmaf(g1.y, ny2[i], db);
            db = fmaf(g1.z, nz2[i], db);
            mn[i] = fminf(mn[i], fminf(da, db));      // -> v_min3_f32
        }
    }

    float* dst = partial + (size_t)blockIdx.y * NQTOT + z * NPTS;
#pragma unroll
    for (int i = 0; i < Q; ++i) {
        dst[i * BLOCK + tid] = fmaxf(p2[i] + mn[i], 0.0f);  // coalesced store
    }
}

// K2: 64 blocks x 1024. Thread j: min over NT chunk-partials, sqrt, then
// deterministic LDS tree-sum -> bsum[block].
__global__ __launch_bounds__(1024) void reduce1_kernel(
    const float* __restrict__ partial, double* __restrict__ bsum)
{
    const int tid = threadIdx.x;
    const int j   = blockIdx.x * 1024 + tid;          // query slot 0..65535

    float m = 3.0e38f;
#pragma unroll 4
    for (int c = 0; c < NT; c += 2) {
        const float a0 = partial[(size_t)c * NQTOT + j];
        const float a1 = partial[(size_t)(c + 1) * NQTOT + j];
        m = fminf(m, fminf(a0, a1));
    }

    __shared__ double sd[1024];
    sd[tid] = (double)sqrtf(m);
    __syncthreads();
    for (int off = 512; off > 0; off >>= 1) {
        if (tid < off) sd[tid] += sd[tid + off];
        __syncthreads();
    }
    if (tid == 0) bsum[blockIdx.x] = sd[0];
}

// K3: one wave sums the 64 block sums (deterministic shuffle tree).
__global__ __launch_bounds__(64) void reduce2_kernel(
    const double* __restrict__ bsum, float* __restrict__ out)
{
    double v = bsum[threadIdx.x];
#pragma unroll
    for (int off = 32; off > 0; off >>= 1) {
        v += __shfl_down(v, off);
    }
    if (threadIdx.x == 0) out[0] = (float)(v / (double)NPER);
}

extern "C" void kernel_launch(void* const* d_in, const int* in_sizes, int n_in,
                              void* d_out, int out_size, void* d_ws, size_t ws_size,
                              hipStream_t stream) {
    const float* pred = (const float*)d_in[0];
    const float* gt   = (const float*)d_in[1];

    float4* pk      = (float4*)d_ws;                       // 1 MB
    float*  partial = (float*)(pk + NQTOT);                // 16 MB
    double* bsum    = (double*)(partial + (size_t)NT * NQTOT);

    pack_kernel<<<NQTOT / 256, 256, 0, stream>>>(pred, gt, pk);

    dim3 grid(1, NT, 2 * BATCH);
    chamfer_min_kernel<<<grid, BLOCK, 0, stream>>>(pk, partial);

    reduce1_kernel<<<NQTOT / 1024, 1024, 0, stream>>>(partial, bsum);
    reduce2_kernel<<<1, 64, 0, stream>>>(bsum, (float*)d_out);
}

// Round 7
// 41.672 us; speedup vs baseline: 3.7011x; 1.2176x over previous
//
#include <hip/hip_runtime.h>

#define BATCH 8
#define NPTS  4096
#define BLOCK 256
#define Q     8              // query points per thread
#define CHUNK 128            // target points staged in LDS per block
#define NQ    2              // query splits  (NQ*BLOCK*Q == NPTS)
#define NT    32             // target splits (NT*CHUNK   == NPTS)
#define NPER  32768          // BATCH*NPTS points per cloud
#define NQTOT (2 * NPER)     // 65536 query slots (both passes)

// ws layout:
//   float4 pk[65536]    : packed [x,y,z,|p|^2]; pred then gt   (1 MB, L2-hot)
//   uint   minbuf[65536]: min d2 bits; pred-queries first, gt-queries second

// K0: pack points into float4 (xyz + squared norm) and init min slots to +inf.
__global__ __launch_bounds__(256) void pack_init_kernel(
    const float* __restrict__ pred, const float* __restrict__ gt,
    float4* __restrict__ pk, unsigned int* __restrict__ minbuf)
{
    const int j = blockIdx.x * 256 + threadIdx.x;     // 0..65535
    const float* src = (j < NPER) ? pred : gt;
    const float* p = src + (size_t)(j & (NPER - 1)) * 3;
    const float x = p[0], y = p[1], z = p[2];
    pk[j] = make_float4(x, y, z, fmaf(x, x, fmaf(y, y, z * z)));
    minbuf[j] = 0x7F800000u;                          // +inf
}

// K1: grid (NQ, NT, 16) = 1024 blocks -> 4 blocks/CU, 4 waves/SIMD.
// Each thread owns Q=8 queries, loops CHUNK=128 targets staged in LDS as
// [gx,gy,gz,g2]; tracks min(g2 - 2 p.g) (3 fma + min per pair of targets),
// folds |p|^2 at the end, clamps at 0, one coalesced atomicMin per query.
__global__ __launch_bounds__(BLOCK) void chamfer_min_kernel(
    const float4* __restrict__ pk, unsigned int* __restrict__ minbuf)
{
    const int z    = blockIdx.z;                      // pass*8 + b
    const int b    = z & 7;
    const int pass = z >> 3;
    const float4* query  = pk + (pass ? NPER : 0) + b * NPTS;
    const float4* target = pk + (pass ? 0 : NPER) + b * NPTS;
    unsigned int* outmin = minbuf + (pass ? NPER : 0) + b * NPTS;

    __shared__ float4 s[CHUNK];

    const int tid   = threadIdx.x;
    const int nbase = blockIdx.x * (BLOCK * Q);
    const int c0    = blockIdx.y * CHUNK;

    if (tid < CHUNK) s[tid] = target[c0 + tid];

    float nx2[Q], ny2[Q], nz2[Q], p2[Q], mn[Q];
#pragma unroll
    for (int i = 0; i < Q; ++i) {
        const float4 qf = query[nbase + i * BLOCK + tid];
        nx2[i] = -2.0f * qf.x;
        ny2[i] = -2.0f * qf.y;
        nz2[i] = -2.0f * qf.z;
        p2[i]  = qf.w;
        mn[i]  = 3.0e38f;
    }
    __syncthreads();

#pragma unroll 4
    for (int t = 0; t < CHUNK; t += 2) {
        const float4 g0 = s[t];
        const float4 g1 = s[t + 1];
#pragma unroll
        for (int i = 0; i < Q; ++i) {
            float da = fmaf(g0.x, nx2[i], g0.w);
            da = fmaf(g0.y, ny2[i], da);
            da = fmaf(g0.z, nz2[i], da);
            float db = fmaf(g1.x, nx2[i], g1.w);
            db = fmaf(g1.y, ny2[i], db);
            db = fmaf(g1.z, nz2[i], db);
            mn[i] = fminf(mn[i], fminf(da, db));      // min3-fusable
        }
    }

#pragma unroll
    for (int i = 0; i < Q; ++i) {
        const float d2 = fmaxf(p2[i] + mn[i], 0.0f);  // min squared distance
        atomicMin(&outmin[nbase + i * BLOCK + tid], __float_as_uint(d2));
    }
}

// K2: deterministic single-block reduction: (sum sqrt(min d2))/32768.
__global__ __launch_bounds__(1024) void chamfer_reduce_kernel(
    const uint4* __restrict__ mins,                   // 65536 uints = 16384 uint4
    float* __restrict__ out)
{
    const int tid = threadIdx.x;
    double acc = 0.0;
#pragma unroll
    for (int i = 0; i < 16; ++i) {
        const uint4 v = mins[tid + i * 1024];
        acc += (double)(sqrtf(__uint_as_float(v.x)) + sqrtf(__uint_as_float(v.y))
                      + sqrtf(__uint_as_float(v.z)) + sqrtf(__uint_as_float(v.w)));
    }
    __shared__ double sd[1024];
    sd[tid] = acc;
    __syncthreads();
    for (int off = 512; off > 0; off >>= 1) {
        if (tid < off) sd[tid] += sd[tid + off];
        __syncthreads();
    }
    if (tid == 0) out[0] = (float)(sd[0] / (double)NPER);
}

extern "C" void kernel_launch(void* const* d_in, const int* in_sizes, int n_in,
                              void* d_out, int out_size, void* d_ws, size_t ws_size,
                              hipStream_t stream) {
    const float* pred = (const float*)d_in[0];
    const float* gt   = (const float*)d_in[1];

    float4* pk           = (float4*)d_ws;                   // 1 MB
    unsigned int* minbuf = (unsigned int*)(pk + NQTOT);     // 256 KB

    pack_init_kernel<<<NQTOT / 256, 256, 0, stream>>>(pred, gt, pk, minbuf);

    dim3 grid(NQ, NT, 2 * BATCH);
    chamfer_min_kernel<<<grid, BLOCK, 0, stream>>>(pk, minbuf);

    chamfer_reduce_kernel<<<1, 1024, 0, stream>>>((const uint4*)minbuf, (float*)d_out);
}

// Round 8
// 36.014 us; speedup vs baseline: 4.2826x; 1.1571x over previous
//
#include <hip/hip_runtime.h>

#define BATCH 8
#define NPTS  4096
#define BLOCK 256
#define Q     8              // query points per thread
#define NQ    2              // query groups   (NQ*BLOCK*Q == NPTS)
#define NT    16             // target chunks  (NT*CHUNK   == NPTS)
#define CHUNK 256            // targets staged in LDS per block
#define NPAIR (CHUNK / 2)    // 128 target PAIRS in LDS
#define NPER  32768          // BATCH*NPTS points per cloud
#define NQTOT (2 * NPER)     // 65536 query slots (both passes)

typedef float f2 __attribute__((ext_vector_type(2)));

// ws layout:
//   float  partial[NT][65536]: per-chunk min DIST (already sqrt'd)   (4 MB)
//   double bsum[64]          : per-block partial sums from reduce1

// K1: grid (NQ, NT, 16) = 512 blocks. Fused: packs its target chunk into LDS
// as float2-pairs [(x0,x1,y0,y1),(z0,z1,w0,w1)], queries into registers as
// duplicated float2 (-2x,-2x).., then per target-pair: 3 v_pk_fma_f32 +
// 1 v_min3_f32 per query (2 VALU instr per pair). Writes sqrt'd chunk-min
// to private partial slice with plain coalesced stores. No atomics, no init.
__global__ __launch_bounds__(BLOCK) void chamfer_min_kernel(
    const float* __restrict__ pred, const float* __restrict__ gt,
    float* __restrict__ partial)
{
    const int z    = blockIdx.z;                      // pass*8 + b
    const int b    = z & 7;
    const int pass = z >> 3;
    const float* query  = (pass ? gt : pred) + (size_t)b * NPTS * 3;
    const float* target = (pass ? pred : gt) + (size_t)b * NPTS * 3;

    __shared__ float4 sA[NPAIR];                      // (x0,x1,y0,y1)
    __shared__ float4 sB[NPAIR];                      // (z0,z1,w0,w1)

    const int tid   = threadIdx.x;
    const int nbase = blockIdx.x * (BLOCK * Q);
    const int c0    = blockIdx.y * CHUNK;

    if (tid < NPAIR) {
        const float* t0 = target + (size_t)(c0 + 2 * tid) * 3;
        const float x0 = t0[0], y0 = t0[1], z0 = t0[2];
        const float x1 = t0[3], y1 = t0[4], z1 = t0[5];
        const float w0 = fmaf(x0, x0, fmaf(y0, y0, z0 * z0));
        const float w1 = fmaf(x1, x1, fmaf(y1, y1, z1 * z1));
        sA[tid] = make_float4(x0, x1, y0, y1);
        sB[tid] = make_float4(z0, z1, w0, w1);
    }

    f2 nx[Q], ny[Q], nz[Q];
    float p2[Q], mn[Q];
#pragma unroll
    for (int i = 0; i < Q; ++i) {
        const float* qp = query + (size_t)(nbase + i * BLOCK + tid) * 3;
        const float x = qp[0], y = qp[1], zz = qp[2];
        nx[i] = (f2){-2.0f * x, -2.0f * x};
        ny[i] = (f2){-2.0f * y, -2.0f * y};
        nz[i] = (f2){-2.0f * zz, -2.0f * zz};
        p2[i] = fmaf(x, x, fmaf(y, y, zz * zz));
        mn[i] = 3.0e38f;
    }
    __syncthreads();

#pragma unroll 4
    for (int j = 0; j < NPAIR; ++j) {
        const float4 a  = sA[j];
        const float4 bb = sB[j];
        const f2 gx = {a.x, a.y};
        const f2 gy = {a.z, a.w};
        const f2 gz = {bb.x, bb.y};
        const f2 gw = {bb.z, bb.w};                   // (g2_0, g2_1)
#pragma unroll
        for (int i = 0; i < Q; ++i) {
            f2 d = __builtin_elementwise_fma(gx, nx[i], gw);
            d = __builtin_elementwise_fma(gy, ny[i], d);
            d = __builtin_elementwise_fma(gz, nz[i], d);
            mn[i] = fminf(mn[i], fminf(d.x, d.y));    // -> v_min3_f32
        }
    }

    float* dst = partial + (size_t)blockIdx.y * NQTOT + (size_t)z * NPTS + nbase;
#pragma unroll
    for (int i = 0; i < Q; ++i) {
        dst[i * BLOCK + tid] = sqrtf(fmaxf(p2[i] + mn[i], 0.0f));
    }
}

// K2: 64 blocks x 1024. Thread j: min over NT chunk-partials (already sqrt'd),
// deterministic LDS tree-sum in double -> bsum[block].
__global__ __launch_bounds__(1024) void reduce1_kernel(
    const float* __restrict__ partial, double* __restrict__ bsum)
{
    const int tid = threadIdx.x;
    const int j   = blockIdx.x * 1024 + tid;          // query slot 0..65535

    float m = 3.0e38f;
#pragma unroll
    for (int c = 0; c < NT; c += 2) {
        const float a0 = partial[(size_t)c * NQTOT + j];
        const float a1 = partial[(size_t)(c + 1) * NQTOT + j];
        m = fminf(m, fminf(a0, a1));
    }

    __shared__ double sd[1024];
    sd[tid] = (double)m;
    __syncthreads();
    for (int off = 512; off > 0; off >>= 1) {
        if (tid < off) sd[tid] += sd[tid + off];
        __syncthreads();
    }
    if (tid == 0) bsum[blockIdx.x] = sd[0];
}

// K3: one wave sums the 64 block sums (deterministic shuffle tree).
__global__ __launch_bounds__(64) void reduce2_kernel(
    const double* __restrict__ bsum, float* __restrict__ out)
{
    double v = bsum[threadIdx.x];
#pragma unroll
    for (int off = 32; off > 0; off >>= 1) {
        v += __shfl_down(v, off);
    }
    if (threadIdx.x == 0) out[0] = (float)(v / (double)NPER);
}

extern "C" void kernel_launch(void* const* d_in, const int* in_sizes, int n_in,
                              void* d_out, int out_size, void* d_ws, size_t ws_size,
                              hipStream_t stream) {
    const float* pred = (const float*)d_in[0];
    const float* gt   = (const float*)d_in[1];

    float*  partial = (float*)d_ws;                         // 4 MB
    double* bsum    = (double*)(partial + (size_t)NT * NQTOT);

    dim3 grid(NQ, NT, 2 * BATCH);
    chamfer_min_kernel<<<grid, BLOCK, 0, stream>>>(pred, gt, partial);

    reduce1_kernel<<<NQTOT / 1024, 1024, 0, stream>>>(partial, bsum);
    reduce2_kernel<<<1, 64, 0, stream>>>(bsum, (float*)d_out);
}